// Round 1
// baseline (5771.474 us; speedup 1.0000x reference)
//
#include <hip/hip_runtime.h>
#include <math.h>

#define NV 500
#define NB 32
#define NT 24
#define NH 64

typedef _Float16 f16;
typedef _Float16 f16x8 __attribute__((ext_vector_type(8)));
typedef _Float16 f16x4 __attribute__((ext_vector_type(4)));
typedef float    f32x4 __attribute__((ext_vector_type(4)));

__device__ __forceinline__ float sigm(float x){ return 1.f/(1.f+expf(-x)); }

// async global->LDS, 16B per lane; LDS dest is wave-uniform base + lane*16
__device__ __forceinline__ void gld16(const f16* g, f16* l)
{
    __builtin_amdgcn_global_load_lds(
        (const __attribute__((address_space(1))) void*)g,
        (__attribute__((address_space(3))) void*)l, 16, 0, 0);
}

// ======================= prep kernels =======================
__global__ void k_a2(const float* __restrict__ A, float* __restrict__ A2)
{
    int idx = blockIdx.x*256 + threadIdx.x;
    if (idx >= 3*500*500) return;
    int wv = idx % 500; int rest = idx/500; int r = rest % 500; int s = rest/500;
    const float* Ar = A + ((size_t)s*500 + r)*500;
    const float* Ac = A + (size_t)s*500*500 + wv;
    float a = 0.f;
    for (int u = 0; u < 500; u++) a += Ar[u]*Ac[(size_t)u*500];
    A2[idx] = a;
}

__global__ void k_acat(const float* __restrict__ A, const float* __restrict__ A2,
                       f16* __restrict__ AcatT)
{
    int idx = blockIdx.x*256 + threadIdx.x;
    if (idx >= 3072*512) return;
    int k = idx & 511;     // v
    int n = idx >> 9;      // j*512 + w
    int j = n >> 9, wv = n & 511;
    float val = 0.f;
    if (k < 500 && wv < 500) {
        int s = j >> 1;
        const float* M = (j & 1) ? A2 : A;
        val = M[((size_t)s*500 + k)*500 + wv];
    }
    AcatT[idx] = (f16)val;
}

__global__ void k_f2h(const float* __restrict__ src, f16* __restrict__ dst, int n)
{
    int idx = blockIdx.x*256 + threadIdx.x;
    if (idx < n) dst[idx] = (f16)src[idx];
}

// ======================= MFMA diffusion GEMM (gload_lds double-buffer) =======================
// A = Acv (Mtot x 512), B = AcatT (3072 x 512), fout[m, n] written at feats layout.
// Linear LDS dest (gload_lds), XOR-swizzle applied to the GLOBAL source chunk and
// to the read side (same involution) -> bank-conflict-free ds_read_b128.
__global__ __launch_bounds__(256)
void k_diff(const f16* __restrict__ Acv, const f16* __restrict__ Bt,
            f16* __restrict__ fout, int Mtot, int C, int G)
{
    __shared__ f16 lds[4*4096];   // buf0{A,B}, buf1{A,B}; 8KB per operand region
    const int tid = threadIdx.x;
    const int n0 = blockIdx.x*128, m0 = blockIdx.y*128;
    const int w = tid>>6, lane = tid&63;

    // staging geometry: inst covers 16 rows/wave; rows ra (inst0), rb=ra+64 (inst1)
    const int ra = w*16 + (lane>>2);
    const int rb = ra + 64;
    const int ca = ((lane&3) ^ ((ra>>1)&3))<<3;   // pre-swizzled source chunk
    const int cb = ((lane&3) ^ ((rb>>1)&3))<<3;
    int mA0 = m0 + ra; if (mA0 > Mtot-1) mA0 = Mtot-1;
    int mA1 = m0 + rb; if (mA1 > Mtot-1) mA1 = Mtot-1;
    const f16* gA0 = Acv + (size_t)mA0*512 + ca;
    const f16* gA1 = Acv + (size_t)mA1*512 + cb;
    const f16* gB0 = Bt + (size_t)(n0+ra)*512 + ca;
    const f16* gB1 = Bt + (size_t)(n0+rb)*512 + cb;
    const int lwb = w*512;        // wave's lds base (f16) within a 2048-f16 half

    const int fm = lane&15, fk = lane>>4;
    const int fch = (fk ^ ((fm>>1)&3))<<3;
    const int wr = (w>>1)<<6, wc = (w&1)<<6;

    f32x4 acc[4][4];
    #pragma unroll
    for (int i=0;i<4;i++)
        #pragma unroll
        for (int j=0;j<4;j++) acc[i][j] = (f32x4){0.f,0.f,0.f,0.f};

    // prologue: stage ks=0 into buf0
    gld16(gA0, lds + lwb);
    gld16(gA1, lds + 2048 + lwb);
    gld16(gB0, lds + 4096 + lwb);
    gld16(gB1, lds + 6144 + lwb);
    __syncthreads();

    #pragma unroll 2
    for (int ks = 0; ks < 16; ks++) {
        const int cur = ks & 1;
        if (ks < 15) {                      // stage next tile into other buffer
            f16* Ln = lds + (cur^1)*8192;
            const int o = (ks+1)*32;
            gld16(gA0 + o, Ln + lwb);
            gld16(gA1 + o, Ln + 2048 + lwb);
            gld16(gB0 + o, Ln + 4096 + lwb);
            gld16(gB1 + o, Ln + 6144 + lwb);
        }
        const f16* La = lds + cur*8192;
        const f16* Lb = La + 4096;
        f16x8 af[4], bf[4];
        #pragma unroll
        for (int i=0;i<4;i++) af[i] = *(const f16x8*)(La + (wr + i*16 + fm)*32 + fch);
        #pragma unroll
        for (int j=0;j<4;j++) bf[j] = *(const f16x8*)(Lb + (wc + j*16 + fm)*32 + fch);
        #pragma unroll
        for (int i=0;i<4;i++)
            #pragma unroll
            for (int j=0;j<4;j++)
                acc[i][j] = __builtin_amdgcn_mfma_f32_16x16x32_f16(af[i], bf[j], acc[i][j], 0, 0, 0);
        __syncthreads();   // drains vmcnt(0)+lgkmcnt(0): next-buf staged, this-buf reads done
    }

    #pragma unroll
    for (int j=0;j<4;j++) {
        int col = n0 + wc + j*16 + fm;
        int jb = col >> 9, wv = col & 511;
        if (wv >= 500) continue;
        #pragma unroll
        for (int i=0;i<4;i++) {
            int mb = m0 + wr + i*16 + fk*4;
            if (C == 64) {
                if (mb >= Mtot) continue;
                int b = mb >> 6, c = mb & 63;
                f16x4 h4;
                h4[0]=(f16)acc[i][j][0]; h4[1]=(f16)acc[i][j][1];
                h4[2]=(f16)acc[i][j][2]; h4[3]=(f16)acc[i][j][3];
                *(f16x4*)(fout + ((size_t)b*512 + wv)*G + C + jb*C + c) = h4;
            } else {
                #pragma unroll
                for (int r=0;r<4;r++) {
                    int m = mb + r;
                    if (m < Mtot) {
                        int b = m / C, c = m - b*C;
                        fout[((size_t)b*512 + wv)*G + C + jb*C + c] = (f16)acc[i][j][r];
                    }
                }
            }
        }
    }
}

// ======================= MFMA gates GEMM (layers 1-3, gload_lds double-buffer) =======================
__global__ __launch_bounds__(256)
void k_gates(const f16* __restrict__ fT, const f16* __restrict__ Wg,
             const float* __restrict__ bg, float* __restrict__ gT)
{
    __shared__ f16 lds[4*4096];
    const int tid = threadIdx.x;
    const int n0 = blockIdx.x*128, m0 = blockIdx.y*128, b = blockIdx.z;
    const f16* Ab = fT + (size_t)b*512*448;
    const int w = tid>>6, lane = tid&63;

    const int ra = w*16 + (lane>>2);
    const int rb = ra + 64;
    const int ca = ((lane&3) ^ ((ra>>1)&3))<<3;
    const int cb = ((lane&3) ^ ((rb>>1)&3))<<3;
    const f16* gA0 = Ab + (size_t)(m0+ra)*448 + ca;
    const f16* gA1 = Ab + (size_t)(m0+rb)*448 + cb;
    const f16* gB0 = Wg + (size_t)(n0+ra)*448 + ca;
    const f16* gB1 = Wg + (size_t)(n0+rb)*448 + cb;
    const int lwb = w*512;

    const int fm = lane&15, fk = lane>>4;
    const int fch = (fk ^ ((fm>>1)&3))<<3;
    const int wr = (w>>1)<<6, wc = (w&1)<<6;

    f32x4 acc[4][4];
    #pragma unroll
    for (int i=0;i<4;i++)
        #pragma unroll
        for (int j=0;j<4;j++) acc[i][j] = (f32x4){0.f,0.f,0.f,0.f};

    gld16(gA0, lds + lwb);
    gld16(gA1, lds + 2048 + lwb);
    gld16(gB0, lds + 4096 + lwb);
    gld16(gB1, lds + 6144 + lwb);
    __syncthreads();

    #pragma unroll 2
    for (int ks = 0; ks < 14; ks++) {
        const int cur = ks & 1;
        if (ks < 13) {
            f16* Ln = lds + (cur^1)*8192;
            const int o = (ks+1)*32;
            gld16(gA0 + o, Ln + lwb);
            gld16(gA1 + o, Ln + 2048 + lwb);
            gld16(gB0 + o, Ln + 4096 + lwb);
            gld16(gB1 + o, Ln + 6144 + lwb);
        }
        const f16* La = lds + cur*8192;
        const f16* Lb = La + 4096;
        f16x8 af[4], bf[4];
        #pragma unroll
        for (int i=0;i<4;i++) af[i] = *(const f16x8*)(La + (wr + i*16 + fm)*32 + fch);
        #pragma unroll
        for (int j=0;j<4;j++) bf[j] = *(const f16x8*)(Lb + (wc + j*16 + fm)*32 + fch);
        #pragma unroll
        for (int i=0;i<4;i++)
            #pragma unroll
            for (int j=0;j<4;j++)
                acc[i][j] = __builtin_amdgcn_mfma_f32_16x16x32_f16(af[i], bf[j], acc[i][j], 0, 0, 0);
        __syncthreads();
    }

    #pragma unroll
    for (int j=0;j<4;j++) {
        int o = n0 + wc + j*16 + fm;
        float bias = bg[o];
        #pragma unroll
        for (int i=0;i<4;i++) {
            int vb = m0 + wr + i*16 + fk*4;
            #pragma unroll
            for (int r=0;r<4;r++) {
                int v = vb + r;
                if (v < 500)
                    gT[((size_t)b*512 + v)*256 + o] = acc[i][j][r] + bias;
            }
        }
    }
}

// ======================= fused LSTM + next-step comb (layers 1-3) =======================
// thread (vl = tid>>2, p = tid&3): 16 channels [p*16, p*16+16) of row v = v0+vl.
// Does: LSTM pointwise; optional h save (channels-last); optional L3 out-projection;
// comb_{t+1} = X[t+1] + h written to featsT cols 0..64 and (via LDS transpose) comb_cv.
__global__ __launch_bounds__(256)
void k_lstmcomb(const float* __restrict__ gT, float* __restrict__ cst,
                const f16* __restrict__ Xn, f16* __restrict__ hsave,
                const float* __restrict__ Wo3, const float* __restrict__ bo3,
                float* __restrict__ out, int t,
                f16* __restrict__ fT, f16* __restrict__ ccv,
                int first, int writecomb)
{
    __shared__ f16 combS[64*68];
    const int b = blockIdx.y, v0 = blockIdx.x*64;
    const int tid = threadIdx.x, vl = tid>>2, p = tid&3;
    const int v = v0 + vl;
    const size_t row = (size_t)b*512 + v;
    const float* g = gT + row*256 + p*16;
    f32x4 g4[4][4];
    #pragma unroll
    for (int q = 0; q < 4; q++)
        #pragma unroll
        for (int k4 = 0; k4 < 4; k4++)
            g4[q][k4] = *(const f32x4*)(g + q*64 + k4*4);

    float* cp = cst + row*64 + p*16;
    float hy[16];
    #pragma unroll
    for (int k4 = 0; k4 < 4; k4++) {
        f32x4 cx4 = first ? (f32x4){0.f,0.f,0.f,0.f} : *(const f32x4*)(cp + k4*4);
        f32x4 cy4;
        #pragma unroll
        for (int e = 0; e < 4; e++) {
            float gi = g4[0][k4][e], gf = g4[1][k4][e], gc = g4[2][k4][e], go = g4[3][k4][e];
            float cy = sigm(gf)*cx4[e] + sigm(gi)*gc;
            cy4[e] = cy;
            hy[k4*4+e] = sigm(go)*tanhf(cy);
        }
        *(f32x4*)(cp + k4*4) = cy4;
    }

    if (hsave) {
        alignas(16) f16 tmp[16];
        #pragma unroll
        for (int k=0;k<16;k++) tmp[k] = (f16)hy[k];
        f16* hp = hsave + row*64 + p*16;
        *(f32x4*)hp = *(f32x4*)tmp;
        *(f32x4*)(hp+8) = *(f32x4*)(tmp+8);
    }

    if (out) {
        float r0 = 0.f, r1 = 0.f;
        #pragma unroll
        for (int k=0;k<16;k++){ r0 += Wo3[p*16+k]*hy[k]; r1 += Wo3[64+p*16+k]*hy[k]; }
        r0 += __shfl_xor(r0, 1, 64); r0 += __shfl_xor(r0, 2, 64);
        r1 += __shfl_xor(r1, 1, 64); r1 += __shfl_xor(r1, 2, 64);
        if (p == 0 && v < 500) {
            out[((size_t)(b*2+0)*500 + v)*24 + t] = r0 + bo3[0];
            out[((size_t)(b*2+1)*500 + v)*24 + t] = r1 + bo3[1];
        }
    }

    if (writecomb) {
        alignas(16) f16 c16[16];
        if (v < 500) {
            const f16* xp = Xn + row*64 + p*16;
            alignas(16) f16 xv[16];
            *(f32x4*)xv = *(const f32x4*)xp;
            *(f32x4*)(xv+8) = *(const f32x4*)(xp+8);
            #pragma unroll
            for (int k=0;k<16;k++) c16[k] = (f16)((float)xv[k] + hy[k]);
        } else {
            #pragma unroll
            for (int k=0;k<16;k++) c16[k] = (f16)0.f;
        }
        f16* fp = fT + row*448 + p*16;
        *(f32x4*)fp = *(f32x4*)c16;
        *(f32x4*)(fp+8) = *(f32x4*)(c16+8);
        #pragma unroll
        for (int k=0;k<16;k++) combS[vl*68 + p*16 + k] = c16[k];
        __syncthreads();
        const int c = tid>>2, j = tid&3;
        alignas(16) f16 tmp[16];
        #pragma unroll
        for (int k=0;k<16;k++) tmp[k] = combS[(j*16+k)*68 + c];
        f16* dst = ccv + ((size_t)b*64 + c)*512 + v0 + j*16;
        *(f32x4*)dst = *(f32x4*)tmp;
        *(f32x4*)(dst+8) = *(f32x4*)(tmp+8);
    }
}

// ======================= seed comb for t=0 (big layers) =======================
__global__ __launch_bounds__(256)
void k_seed(const f16* __restrict__ X0, f16* __restrict__ fT, f16* __restrict__ ccv)
{
    __shared__ f16 combS[64*68];
    const int b = blockIdx.y, v0 = blockIdx.x*64;
    const int tid = threadIdx.x, vl = tid>>2, p = tid&3;
    const int v = v0 + vl;
    const size_t row = (size_t)b*512 + v;
    alignas(16) f16 c16[16];
    if (v < 500) {
        const f16* xp = X0 + row*64 + p*16;
        *(f32x4*)c16 = *(const f32x4*)xp;
        *(f32x4*)(c16+8) = *(const f32x4*)(xp+8);
    } else {
        #pragma unroll
        for (int k=0;k<16;k++) c16[k] = (f16)0.f;
    }
    f16* fp = fT + row*448 + p*16;
    *(f32x4*)fp = *(f32x4*)c16;
    *(f32x4*)(fp+8) = *(f32x4*)(c16+8);
    #pragma unroll
    for (int k=0;k<16;k++) combS[vl*68 + p*16 + k] = c16[k];
    __syncthreads();
    const int c = tid>>2, j = tid&3;
    alignas(16) f16 tmp[16];
    #pragma unroll
    for (int k=0;k<16;k++) tmp[k] = combS[(j*16+k)*68 + c];
    f16* dst = ccv + ((size_t)b*64 + c)*512 + v0 + j*16;
    *(f32x4*)dst = *(f32x4*)tmp;
    *(f32x4*)(dst+8) = *(f32x4*)(tmp+8);
}

// ======================= batched input projection X[t] = se*(Wo.src[t] + bo) =======================
// grid (8 vtiles, NB, T); output X (t,b,v,64) f16, channels-last.
__global__ __launch_bounds__(256)
void k_xproj(const void* __restrict__ src, int srcF16, int Cin,
             const float* __restrict__ Wo, const float* __restrict__ bo,
             const float* __restrict__ se, f16* __restrict__ X)
{
    __shared__ float WoS[64*64];
    __shared__ float boS[64], seS[64];
    const int b = blockIdx.y, t = blockIdx.z, v0 = blockIdx.x*64;
    const int tid = threadIdx.x;
    for (int i = tid; i < 64*Cin; i += 256) WoS[i] = Wo[i];
    if (tid < 64) { boS[tid] = bo[tid]; seS[tid] = se ? se[b*64+tid] : 1.f; }
    __syncthreads();
    const int vl = tid>>2, p = tid&3;
    const int v = v0 + vl;
    const size_t row = ((size_t)t*NB + b)*512 + v;
    float acc[16];
    #pragma unroll
    for (int k=0;k<16;k++) acc[k] = 0.f;
    if (srcF16) {
        const f16* sp = (const f16*)src + row*Cin;
        for (int cc = 0; cc < Cin; cc++) {
            float xv = (float)sp[cc];
            #pragma unroll
            for (int k=0;k<16;k++) acc[k] += WoS[(p*16+k)*Cin + cc]*xv;
        }
    } else {
        const float* sp = (const float*)src + row*Cin;
        for (int cc = 0; cc < Cin; cc++) {
            float xv = sp[cc];
            #pragma unroll
            for (int k=0;k<16;k++) acc[k] += WoS[(p*16+k)*Cin + cc]*xv;
        }
    }
    alignas(16) f16 o16[16];
    #pragma unroll
    for (int k=0;k<16;k++) { int c = p*16+k; o16[k] = (f16)(seS[c]*(acc[k] + boS[c])); }
    f16* xp = X + row*64 + p*16;
    *(f32x4*)xp = *(f32x4*)o16;
    *(f32x4*)(xp+8) = *(f32x4*)(o16+8);
}

// ======================= layer 0 =======================
// XE[t,b,v,6]: x + weather embedding, all timesteps (float)
__global__ void k_xe(const float* __restrict__ x, const int* __restrict__ wt,
                     const float* __restrict__ Wemb, float* __restrict__ XE)
{
    int id = blockIdx.x*256 + threadIdx.x;
    if (id >= NT*NB*512) return;
    int v = id & 511; int r = id >> 9; int b = r & 31; int t = r >> 5;
    float vals[6] = {0.f,0.f,0.f,0.f,0.f,0.f};
    if (v < 500) {
        vals[0] = x[((size_t)(b*2+0)*500 + v)*24 + t];
        vals[1] = x[((size_t)(b*2+1)*500 + v)*24 + t];
        int wty = wt[((size_t)b*500 + v)*24 + t];
        vals[2] = Wemb[wty*4+0]; vals[3] = Wemb[wty*4+1];
        vals[4] = Wemb[wty*4+2]; vals[5] = Wemb[wty*4+3];
    }
    float* xe = XE + (size_t)id*6;
    #pragma unroll
    for (int c = 0; c < 6; c++) xe[c] = vals[c];
}

__global__ void k_seed0(const float* __restrict__ XE, f16* __restrict__ f0T,
                        f16* __restrict__ ccv0)
{
    int id = blockIdx.x*256 + threadIdx.x;
    if (id >= NB*512) return;
    int v = id & 511, b = id >> 9;
    const float* xe = XE + (size_t)id*6;
    #pragma unroll
    for (int c = 0; c < 6; c++) {
        f16 h = (v < 500) ? (f16)xe[c] : (f16)0.f;
        f0T[(size_t)id*42 + c] = h;
        ccv0[((size_t)b*6 + c)*512 + v] = h;
    }
}

// fused gates0 + lstm0 + next-step comb0. f0T is read AND written (cols 0..6).
__global__ __launch_bounds__(256)
void k_glstm0(f16* f0T, const float* __restrict__ Wg0,
              const float* __restrict__ bg0, float* __restrict__ cst0,
              float* __restrict__ hs0T, const float* __restrict__ XE,
              f16* __restrict__ ccv0, int t)
{
    __shared__ float WgS[24*42];
    __shared__ float bgS[24];
    int tid = threadIdx.x;
    for (int i = tid; i < 24*42; i += 256) WgS[i] = Wg0[i];
    if (tid < 24) bgS[tid] = bg0[tid];
    __syncthreads();
    int id = blockIdx.x*256 + tid;
    if (id >= NB*500) return;
    int b = id / 500, v = id - b*500;
    const f16* fp = f0T + ((size_t)b*512 + v)*42;
    float fv[42];
    #pragma unroll
    for (int g = 0; g < 42; g++) fv[g] = (float)fp[g];
    float gates[24];
    #pragma unroll
    for (int o = 0; o < 24; o++) {
        float a = bgS[o];
        #pragma unroll
        for (int g = 0; g < 42; g++) a += WgS[o*42+g]*fv[g];
        gates[o] = a;
    }
    size_t hrow = (((size_t)t*NB + b)*512 + v)*6;
    const float* xe = XE + (((size_t)(t+1)*NB + b)*512 + v)*6;   // only read if t<23
    #pragma unroll
    for (int c = 0; c < 6; c++) {
        size_t ci = ((size_t)b*500 + v)*6 + c;
        float cx = t ? cst0[ci] : 0.f;
        float cy = sigm(gates[6+c])*cx + sigm(gates[c])*gates[12+c];
        cst0[ci] = cy;
        float h = sigm(gates[18+c])*tanhf(cy);
        hs0T[hrow + c] = h;
        if (t < 23) {
            float cmb = xe[c] + h;
            f0T[((size_t)b*512 + v)*42 + c] = (f16)cmb;
            ccv0[((size_t)b*6 + c)*512 + v] = (f16)cmb;
        }
    }
}

// ======================= SE path =======================
__global__ void k_mean0(const float* __restrict__ hs0T, float* __restrict__ mean0)
{
    int b = blockIdx.x;
    float acc[6] = {0,0,0,0,0,0};
    for (int i = threadIdx.x; i < 24*500; i += 256) {
        int tt = i/500, v = i - tt*500;
        const float* p = hs0T + (((size_t)tt*NB + b)*512 + v)*6;
        #pragma unroll
        for (int c=0;c<6;c++) acc[c] += p[c];
    }
    __shared__ float red[256];
    for (int c=0;c<6;c++) {
        red[threadIdx.x] = acc[c]; __syncthreads();
        for (int s=128;s>0;s>>=1) { if (threadIdx.x<s) red[threadIdx.x]+=red[threadIdx.x+s]; __syncthreads(); }
        if (threadIdx.x==0) mean0[b*6+c] = red[0]/12000.f;
        __syncthreads();
    }
}

__global__ void k_mean1(const f16* __restrict__ hs1T, float* __restrict__ mean1)
{
    int cg = blockIdx.x, b = blockIdx.y;
    float acc[8] = {0,0,0,0,0,0,0,0};
    for (int i = threadIdx.x; i < 24*500; i += 256) {
        int tt = i/500, v = i - tt*500;
        const f16* p = hs1T + (((size_t)tt*NB + b)*512 + v)*64 + cg*8;
        #pragma unroll
        for (int c=0;c<8;c++) acc[c] += (float)p[c];
    }
    __shared__ float red[256];
    for (int c=0;c<8;c++) {
        red[threadIdx.x] = acc[c]; __syncthreads();
        for (int s=128;s>0;s>>=1) { if (threadIdx.x<s) red[threadIdx.x]+=red[threadIdx.x+s]; __syncthreads(); }
        if (threadIdx.x==0) mean1[b*64 + cg*8 + c] = red[0]/12000.f;
        __syncthreads();
    }
}

__global__ void k_se(const float* __restrict__ meanhs, const float* __restrict__ Wo,
                     const float* __restrict__ bo, int Cin,
                     const float* __restrict__ Wa, const float* __restrict__ Wb,
                     float* __restrict__ se)
{
    int b = blockIdx.x; int c = threadIdx.x;
    __shared__ float y[64]; __shared__ float a[4];
    float acc = bo[c];
    for (int j = 0; j < Cin; j++) acc += Wo[(size_t)c*Cin + j] * meanhs[b*Cin + j];
    y[c] = acc;
    __syncthreads();
    if (c < 4) {
        float s = 0.f;
        for (int j = 0; j < 64; j++) s += Wa[c*64 + j] * y[j];
        a[c] = fmaxf(s, 0.f);
    }
    __syncthreads();
    float s = 0.f;
    #pragma unroll
    for (int j = 0; j < 4; j++) s += Wb[c*4 + j] * a[j];
    se[b*64 + c] = 1.f/(1.f + expf(-s));
}

// ======================= host launch =======================
extern "C" void kernel_launch(void* const* d_in, const int* in_sizes, int n_in,
                              void* d_out, int out_size, void* d_ws, size_t ws_size,
                              hipStream_t stream)
{
    const float* x    = (const float*)d_in[0];
    const float* sup  = (const float*)d_in[1];
    const int*   wt   = (const int*)  d_in[2];
    const float* Wemb = (const float*)d_in[3];
    const float* Wg0  = (const float*)d_in[4];
    const float* bg0  = (const float*)d_in[5];
    const float* Wo0  = (const float*)d_in[6];
    const float* bo0  = (const float*)d_in[7];
    const float* Wa0  = (const float*)d_in[8];
    const float* Wb0  = (const float*)d_in[9];
    const float* Wg1  = (const float*)d_in[10];
    const float* bg1  = (const float*)d_in[11];
    const float* Wo1  = (const float*)d_in[12];
    const float* bo1  = (const float*)d_in[13];
    const float* Wa1  = (const float*)d_in[14];
    const float* Wb1  = (const float*)d_in[15];
    const float* Wg2  = (const float*)d_in[16];
    const float* bg2  = (const float*)d_in[17];
    const float* Wo2  = (const float*)d_in[18];
    const float* bo2  = (const float*)d_in[19];
    const float* Wg3  = (const float*)d_in[20];
    const float* bg3  = (const float*)d_in[21];
    const float* Wo3  = (const float*)d_in[22];
    const float* bo3  = (const float*)d_in[23];
    float* out = (float*)d_out;
    (void)in_sizes; (void)n_in; (void)out_size; (void)ws_size;

    char* ws = (char*)d_ws;
    size_t off = 0;
    f16*   AcatT  = (f16*)(ws + off);   off += (size_t)3072*512*2;
    float* A2     = (float*)(ws + off); off += (size_t)3*500*500*4;
    f16*   WgF1   = (f16*)(ws + off);   off += (size_t)256*448*2;
    f16*   WgF2   = (f16*)(ws + off);   off += (size_t)256*448*2;
    f16*   WgF3   = (f16*)(ws + off);   off += (size_t)256*448*2;
    f16*   comb_cv= (f16*)(ws + off);   off += (size_t)2048*512*2;
    f16*   ccv0   = (f16*)(ws + off);   off += (size_t)192*512*2;
    f16*   featsT = (f16*)(ws + off);   off += (size_t)NB*512*448*2;
    f16*   f0T    = (f16*)(ws + off);   off += (size_t)NB*512*42*2;
    float* gatesT = (float*)(ws + off); off += (size_t)NB*512*256*4;
    float* hs0T   = (float*)(ws + off); off += (size_t)NT*NB*512*6*4;
    f16*   hs1T   = (f16*)(ws + off);   off += (size_t)NT*NB*512*64*2;
    f16*   hT     = (f16*)(ws + off);   off += (size_t)NB*512*64*2;
    float* cstT   = (float*)(ws + off); off += (size_t)NB*512*64*4;
    float* cst0   = (float*)(ws + off); off += (size_t)NB*500*6*4;
    f16*   Xbuf   = (f16*)(ws + off);   off += (size_t)NT*NB*512*64*2;
    f16*   X3     = (f16*)(ws + off);   off += (size_t)NB*512*64*2;
    float* mean0  = (float*)(ws + off); off += 8192;
    float* se0    = (float*)(ws + off); off += 8192;
    float* mean1  = (float*)(ws + off); off += 8192;
    float* se1    = (float*)(ws + off); off += 8192;

    // XE (24x32x512x6 f32 = 9.4 MB) aliases gatesT (16.8 MB): XE is dead before
    // the first k_gates write (L0 phase strictly precedes layer 1).
    float* XE = gatesT;

    const size_t sliceH = (size_t)NB*512*64;   // f16 elements per timestep slice

    // ---- prep ----
    k_a2  <<<(3*500*500 + 255)/256, 256, 0, stream>>>(sup, A2);
    k_acat<<<(3072*512 + 255)/256, 256, 0, stream>>>(sup, A2, AcatT);
    k_f2h <<<(256*448 + 255)/256, 256, 0, stream>>>(Wg1, WgF1, 256*448);
    k_f2h <<<(256*448 + 255)/256, 256, 0, stream>>>(Wg2, WgF2, 256*448);
    k_f2h <<<(256*448 + 255)/256, 256, 0, stream>>>(Wg3, WgF3, 256*448);
    k_xe  <<<(NT*NB*512)/256, 256, 0, stream>>>(x, wt, Wemb, XE);

    // ---- layer 0 ----
    k_seed0<<<(NB*512)/256, 256, 0, stream>>>(XE, f0T, ccv0);
    for (int t = 0; t < NT; t++) {
        k_diff  <<<dim3(24, 2), 256, 0, stream>>>(ccv0, AcatT, f0T, 192, 6, 42);
        k_glstm0<<<(NB*500 + 255)/256, 256, 0, stream>>>(f0T, Wg0, bg0, cst0, hs0T, XE, ccv0, t);
    }
    k_mean0<<<NB, 256, 0, stream>>>(hs0T, mean0);
    k_se   <<<NB, 64, 0, stream>>>(mean0, Wo0, bo0, 6, Wa0, Wb0, se0);

    // ---- layer 1 ----
    k_xproj<<<dim3(8, NB, NT), 256, 0, stream>>>(hs0T, 0, 6, Wo0, bo0, se0, Xbuf);
    k_seed <<<dim3(8, NB), 256, 0, stream>>>(Xbuf, featsT, comb_cv);
    for (int t = 0; t < NT; t++) {
        k_diff <<<dim3(24, 16), 256, 0, stream>>>(comb_cv, AcatT, featsT, 2048, 64, 448);
        k_gates<<<dim3(2, 4, NB), 256, 0, stream>>>(featsT, WgF1, bg1, gatesT);
        k_lstmcomb<<<dim3(8, NB), 256, 0, stream>>>(gatesT, cstT,
                 (t < 23) ? Xbuf + (size_t)(t+1)*sliceH : (const f16*)nullptr,
                 hs1T + (size_t)t*sliceH, nullptr, nullptr, nullptr, t,
                 featsT, comb_cv, t == 0, t < 23);
    }
    k_mean1<<<dim3(8, NB), 256, 0, stream>>>(hs1T, mean1);
    k_se   <<<NB, 64, 0, stream>>>(mean1, Wo1, bo1, 64, Wa1, Wb1, se1);

    // ---- layer 2 ----
    k_xproj<<<dim3(8, NB, NT), 256, 0, stream>>>(hs1T, 1, 64, Wo1, bo1, se1, Xbuf);
    k_seed <<<dim3(8, NB), 256, 0, stream>>>(Xbuf, featsT, comb_cv);
    for (int t = 0; t < NT; t++) {
        k_diff <<<dim3(24, 16), 256, 0, stream>>>(comb_cv, AcatT, featsT, 2048, 64, 448);
        k_gates<<<dim3(2, 4, NB), 256, 0, stream>>>(featsT, WgF2, bg2, gatesT);
        k_lstmcomb<<<dim3(8, NB), 256, 0, stream>>>(gatesT, cstT,
                 (t < 23) ? Xbuf + (size_t)(t+1)*sliceH : (const f16*)nullptr,
                 hT, nullptr, nullptr, nullptr, t,
                 featsT, comb_cv, t == 0, t < 23);
    }

    // ---- layer 3 (final, fixed input x3 = Wo2.h2_last + bo2) ----
    k_xproj<<<dim3(8, NB, 1), 256, 0, stream>>>(hT, 1, 64, Wo2, bo2, nullptr, X3);
    k_seed <<<dim3(8, NB), 256, 0, stream>>>(X3, featsT, comb_cv);
    for (int t = 0; t < NT; t++) {
        k_diff <<<dim3(24, 16), 256, 0, stream>>>(comb_cv, AcatT, featsT, 2048, 64, 448);
        k_gates<<<dim3(2, 4, NB), 256, 0, stream>>>(featsT, WgF3, bg3, gatesT);
        k_lstmcomb<<<dim3(8, NB), 256, 0, stream>>>(gatesT, cstT, X3,
                 nullptr, Wo3, bo3, out, t,
                 featsT, comb_cv, t == 0, t < 23);
    }
}

// Round 2
// 4789.964 us; speedup vs baseline: 1.2049x; 1.2049x over previous
//
#include <hip/hip_runtime.h>
#include <math.h>

#define NV 500
#define NB 32
#define NT 24
#define NH 64

typedef _Float16 f16;
typedef _Float16 f16x8 __attribute__((ext_vector_type(8)));
typedef _Float16 f16x4 __attribute__((ext_vector_type(4)));
typedef float    f32x4 __attribute__((ext_vector_type(4)));

__device__ __forceinline__ float sigm(float x){ return 1.f/(1.f+expf(-x)); }

// ======================= prep kernels =======================
__global__ void k_a2(const float* __restrict__ A, float* __restrict__ A2)
{
    int idx = blockIdx.x*256 + threadIdx.x;
    if (idx >= 3*500*500) return;
    int wv = idx % 500; int rest = idx/500; int r = rest % 500; int s = rest/500;
    const float* Ar = A + ((size_t)s*500 + r)*500;
    const float* Ac = A + (size_t)s*500*500 + wv;
    float a = 0.f;
    for (int u = 0; u < 500; u++) a += Ar[u]*Ac[(size_t)u*500];
    A2[idx] = a;
}

__global__ void k_acat(const float* __restrict__ A, const float* __restrict__ A2,
                       f16* __restrict__ AcatT)
{
    int idx = blockIdx.x*256 + threadIdx.x;
    if (idx >= 3072*512) return;
    int k = idx & 511;     // v
    int n = idx >> 9;      // j*512 + w
    int j = n >> 9, wv = n & 511;
    float val = 0.f;
    if (k < 500 && wv < 500) {
        int s = j >> 1;
        const float* M = (j & 1) ? A2 : A;
        val = M[((size_t)s*500 + k)*500 + wv];
    }
    AcatT[idx] = (f16)val;
}

__global__ void k_f2h(const float* __restrict__ src, f16* __restrict__ dst, int n)
{
    int idx = blockIdx.x*256 + threadIdx.x;
    if (idx < n) dst[idx] = (f16)src[idx];
}

// ======================= MFMA diffusion GEMM (proven reg-staged structure) =======================
__global__ __launch_bounds__(256)
void k_diff(const f16* __restrict__ Acv, const f16* __restrict__ Bt,
            f16* __restrict__ fout, int Mtot, int C, int G)
{
    __shared__ f16 lA[128*32];
    __shared__ f16 lB[128*32];
    const int tid = threadIdx.x;
    const int n0 = blockIdx.x*128, m0 = blockIdx.y*128;
    const int r0 = tid>>2, c0 = tid&3;
    const int swz0 = r0*32 + ((c0 ^ ((r0>>1)&3))<<3);
    const int swz1 = swz0 + 64*32;
    int mA0 = m0 + r0;      if (mA0 > Mtot-1) mA0 = Mtot-1;
    int mA1 = m0 + r0 + 64; if (mA1 > Mtot-1) mA1 = Mtot-1;
    const f16* gA0 = Acv + (size_t)mA0*512 + c0*8;
    const f16* gA1 = Acv + (size_t)mA1*512 + c0*8;
    const f16* gB0 = Bt + (size_t)(n0+r0)*512 + c0*8;
    const f16* gB1 = Bt + (size_t)(n0+r0+64)*512 + c0*8;

    const int w = tid>>6, lane = tid&63;
    const int wr = (w>>1)<<6, wc = (w&1)<<6;
    const int fm = lane&15, fk = lane>>4;
    const int fch = (fk ^ ((fm>>1)&3))<<3;

    f32x4 acc[4][4];
    #pragma unroll
    for (int i=0;i<4;i++)
        #pragma unroll
        for (int j=0;j<4;j++) acc[i][j] = (f32x4){0.f,0.f,0.f,0.f};

    f32x4 ra0 = *(const f32x4*)gA0, ra1 = *(const f32x4*)gA1;
    f32x4 rb0 = *(const f32x4*)gB0, rb1 = *(const f32x4*)gB1;

    for (int ks = 0; ks < 16; ks++) {
        __syncthreads();
        *(f32x4*)(lA + swz0) = ra0;  *(f32x4*)(lA + swz1) = ra1;
        *(f32x4*)(lB + swz0) = rb0;  *(f32x4*)(lB + swz1) = rb1;
        if (ks < 15) {
            int o = (ks+1)*32;
            ra0 = *(const f32x4*)(gA0 + o); ra1 = *(const f32x4*)(gA1 + o);
            rb0 = *(const f32x4*)(gB0 + o); rb1 = *(const f32x4*)(gB1 + o);
        }
        __syncthreads();
        f16x8 af[4], bf[4];
        #pragma unroll
        for (int i=0;i<4;i++) af[i] = *(const f16x8*)(lA + (wr + i*16 + fm)*32 + fch);
        #pragma unroll
        for (int j=0;j<4;j++) bf[j] = *(const f16x8*)(lB + (wc + j*16 + fm)*32 + fch);
        #pragma unroll
        for (int i=0;i<4;i++)
            #pragma unroll
            for (int j=0;j<4;j++)
                acc[i][j] = __builtin_amdgcn_mfma_f32_16x16x32_f16(af[i], bf[j], acc[i][j], 0, 0, 0);
    }

    #pragma unroll
    for (int j=0;j<4;j++) {
        int col = n0 + wc + j*16 + fm;
        int jb = col >> 9, wv = col & 511;
        if (wv >= 500) continue;
        #pragma unroll
        for (int i=0;i<4;i++) {
            int mb = m0 + wr + i*16 + fk*4;
            if (C == 64) {
                if (mb >= Mtot) continue;
                int b = mb >> 6, c = mb & 63;
                f16x4 h4;
                h4[0]=(f16)acc[i][j][0]; h4[1]=(f16)acc[i][j][1];
                h4[2]=(f16)acc[i][j][2]; h4[3]=(f16)acc[i][j][3];
                *(f16x4*)(fout + ((size_t)b*512 + wv)*G + C + jb*C + c) = h4;
            } else {
                #pragma unroll
                for (int r=0;r<4;r++) {
                    int m = mb + r;
                    if (m < Mtot) {
                        int b = m / C, c = m - b*C;
                        fout[((size_t)b*512 + wv)*G + C + jb*C + c] = (f16)acc[i][j][r];
                    }
                }
            }
        }
    }
}

// ======================= fused gates GEMM + LSTM + next comb (layers 1-3) =======================
// Block: 64 vertices (m0 = blockIdx.x*64) x all 256 gate channels, batch b = blockIdx.y.
// Wave w computes gate quadrant w (i/f/c/o). Accumulators exchanged via LDS, then the
// LSTM pointwise, h save, optional L3 out-projection, and next-step comb (both layouts).
__global__ __launch_bounds__(256)
void k_gateslstm(const f16* __restrict__ fT, const f16* __restrict__ Wg,
                 const float* __restrict__ bg, float* __restrict__ cst,
                 const f16* __restrict__ Xn, f16* __restrict__ hsave,
                 const float* __restrict__ Wo3, const float* __restrict__ bo3,
                 float* __restrict__ out, int t,
                 f16* __restrict__ fTout, f16* __restrict__ ccv,
                 int first, int writecomb)
{
    __shared__ f16 lA[64*32];
    __shared__ f16 lB[256*32];
    __shared__ float ExF[4*64*65];   // [quad][vertex][chan] padded
    __shared__ float bgS[256];
    __shared__ f16 combS[64*68];
    const int tid = threadIdx.x;
    const int m0 = blockIdx.x*64, b = blockIdx.y;
    const f16* Ab = fT + (size_t)b*512*448;
    bgS[tid] = bg[tid];

    const int r0 = tid>>2, c0 = tid&3;
    const int swz = r0*32 + ((c0 ^ ((r0>>1)&3))<<3);
    const f16* gA = Ab + (size_t)(m0+r0)*448 + c0*8;
    const f16* gB = Wg + (size_t)r0*448 + c0*8;

    const int w = tid>>6, lane = tid&63;
    const int wc = w<<6;
    const int fm = lane&15, fk = lane>>4;
    const int fch = (fk ^ ((fm>>1)&3))<<3;

    f32x4 acc[4][4];
    #pragma unroll
    for (int i=0;i<4;i++)
        #pragma unroll
        for (int j=0;j<4;j++) acc[i][j] = (f32x4){0.f,0.f,0.f,0.f};

    f32x4 ra  = *(const f32x4*)gA;
    f32x4 rb0 = *(const f32x4*)gB;
    f32x4 rb1 = *(const f32x4*)(gB + (size_t)64*448);
    f32x4 rb2 = *(const f32x4*)(gB + (size_t)128*448);
    f32x4 rb3 = *(const f32x4*)(gB + (size_t)192*448);

    for (int ks = 0; ks < 14; ks++) {
        __syncthreads();
        *(f32x4*)(lA + swz) = ra;
        *(f32x4*)(lB + swz)          = rb0;
        *(f32x4*)(lB + 64*32 + swz)  = rb1;
        *(f32x4*)(lB + 128*32 + swz) = rb2;
        *(f32x4*)(lB + 192*32 + swz) = rb3;
        if (ks < 13) {
            int o = (ks+1)*32;
            ra  = *(const f32x4*)(gA + o);
            rb0 = *(const f32x4*)(gB + o);
            rb1 = *(const f32x4*)(gB + (size_t)64*448 + o);
            rb2 = *(const f32x4*)(gB + (size_t)128*448 + o);
            rb3 = *(const f32x4*)(gB + (size_t)192*448 + o);
        }
        __syncthreads();
        f16x8 af[4], bf[4];
        #pragma unroll
        for (int i=0;i<4;i++) af[i] = *(const f16x8*)(lA + (i*16 + fm)*32 + fch);
        #pragma unroll
        for (int j=0;j<4;j++) bf[j] = *(const f16x8*)(lB + (wc + j*16 + fm)*32 + fch);
        #pragma unroll
        for (int i=0;i<4;i++)
            #pragma unroll
            for (int j=0;j<4;j++)
                acc[i][j] = __builtin_amdgcn_mfma_f32_16x16x32_f16(af[i], bf[j], acc[i][j], 0, 0, 0);
    }

    // exchange accumulators: ExF[quad w][vertex][chan-within-quad]
    __syncthreads();
    #pragma unroll
    for (int i=0;i<4;i++)
        #pragma unroll
        for (int j=0;j<4;j++)
            #pragma unroll
            for (int r=0;r<4;r++)
                ExF[((w<<6) + i*16 + (fk<<2) + r)*65 + (j<<4) + fm] = acc[i][j][r];
    __syncthreads();

    // LSTM pointwise: thread owns 16 channels [p*16, p*16+16) of vertex vl
    const int vl = tid>>2, p = tid&3;
    const int v = m0 + vl;
    const size_t row = (size_t)b*512 + v;
    float hy[16];
    float* cp = cst + row*64 + (p<<4);
    #pragma unroll
    for (int k4=0;k4<4;k4++) {
        f32x4 cx4 = first ? (f32x4){0.f,0.f,0.f,0.f} : *(const f32x4*)(cp + k4*4);
        f32x4 cy4;
        #pragma unroll
        for (int e=0;e<4;e++) {
            int c = (p<<4) + k4*4 + e;
            float gi = ExF[(         vl)*65 + c] + bgS[c];
            float gf = ExF[( 64 +    vl)*65 + c] + bgS[64+c];
            float gc = ExF[(128 +    vl)*65 + c] + bgS[128+c];
            float go = ExF[(192 +    vl)*65 + c] + bgS[192+c];
            float cy = sigm(gf)*cx4[e] + sigm(gi)*gc;
            cy4[e] = cy;
            hy[k4*4+e] = sigm(go)*tanhf(cy);
        }
        *(f32x4*)(cp + k4*4) = cy4;
    }

    if (hsave) {
        alignas(16) f16 tmp[16];
        #pragma unroll
        for (int k=0;k<16;k++) tmp[k] = (f16)hy[k];
        f16* hp = hsave + row*64 + (p<<4);
        *(f32x4*)hp = *(f32x4*)tmp;
        *(f32x4*)(hp+8) = *(f32x4*)(tmp+8);
    }

    if (out) {
        float r0s = 0.f, r1s = 0.f;
        #pragma unroll
        for (int k=0;k<16;k++){ r0s += Wo3[(p<<4)+k]*hy[k]; r1s += Wo3[64+(p<<4)+k]*hy[k]; }
        r0s += __shfl_xor(r0s, 1, 64); r0s += __shfl_xor(r0s, 2, 64);
        r1s += __shfl_xor(r1s, 1, 64); r1s += __shfl_xor(r1s, 2, 64);
        if (p == 0 && v < 500) {
            out[((size_t)(b*2+0)*500 + v)*24 + t] = r0s + bo3[0];
            out[((size_t)(b*2+1)*500 + v)*24 + t] = r1s + bo3[1];
        }
    }

    if (writecomb) {
        alignas(16) f16 c16[16];
        if (v < 500) {
            const f16* xp = Xn + row*64 + (p<<4);
            alignas(16) f16 xv[16];
            *(f32x4*)xv = *(const f32x4*)xp;
            *(f32x4*)(xv+8) = *(const f32x4*)(xp+8);
            #pragma unroll
            for (int k=0;k<16;k++) c16[k] = (f16)((float)xv[k] + hy[k]);
        } else {
            #pragma unroll
            for (int k=0;k<16;k++) c16[k] = (f16)0.f;
        }
        f16* fp = fTout + row*448 + (p<<4);
        *(f32x4*)fp = *(f32x4*)c16;
        *(f32x4*)(fp+8) = *(f32x4*)(c16+8);
        #pragma unroll
        for (int k=0;k<16;k++) combS[vl*68 + (p<<4) + k] = c16[k];
        __syncthreads();
        const int c = tid>>2, jj = tid&3;
        alignas(16) f16 tmp[16];
        #pragma unroll
        for (int k=0;k<16;k++) tmp[k] = combS[(jj*16+k)*68 + c];
        f16* dst = ccv + ((size_t)b*64 + c)*512 + m0 + jj*16;
        *(f32x4*)dst = *(f32x4*)tmp;
        *(f32x4*)(dst+8) = *(f32x4*)(tmp+8);
    }
}

// ======================= seed comb for t=0 (big layers) =======================
__global__ __launch_bounds__(256)
void k_seed(const f16* __restrict__ X0, f16* __restrict__ fT, f16* __restrict__ ccv)
{
    __shared__ f16 combS[64*68];
    const int b = blockIdx.y, v0 = blockIdx.x*64;
    const int tid = threadIdx.x, vl = tid>>2, p = tid&3;
    const int v = v0 + vl;
    const size_t row = (size_t)b*512 + v;
    alignas(16) f16 c16[16];
    if (v < 500) {
        const f16* xp = X0 + row*64 + p*16;
        *(f32x4*)c16 = *(const f32x4*)xp;
        *(f32x4*)(c16+8) = *(const f32x4*)(xp+8);
    } else {
        #pragma unroll
        for (int k=0;k<16;k++) c16[k] = (f16)0.f;
    }
    f16* fp = fT + row*448 + p*16;
    *(f32x4*)fp = *(f32x4*)c16;
    *(f32x4*)(fp+8) = *(f32x4*)(c16+8);
    #pragma unroll
    for (int k=0;k<16;k++) combS[vl*68 + p*16 + k] = c16[k];
    __syncthreads();
    const int c = tid>>2, j = tid&3;
    alignas(16) f16 tmp[16];
    #pragma unroll
    for (int k=0;k<16;k++) tmp[k] = combS[(j*16+k)*68 + c];
    f16* dst = ccv + ((size_t)b*64 + c)*512 + v0 + j*16;
    *(f32x4*)dst = *(f32x4*)tmp;
    *(f32x4*)(dst+8) = *(f32x4*)(tmp+8);
}

// ======================= batched input projection X[t] = se*(Wo.src[t] + bo) =======================
__global__ __launch_bounds__(256)
void k_xproj(const void* __restrict__ src, int srcF16, int Cin,
             const float* __restrict__ Wo, const float* __restrict__ bo,
             const float* __restrict__ se, f16* __restrict__ X)
{
    __shared__ float WoS[64*64];
    __shared__ float boS[64], seS[64];
    const int b = blockIdx.y, t = blockIdx.z, v0 = blockIdx.x*64;
    const int tid = threadIdx.x;
    for (int i = tid; i < 64*Cin; i += 256) WoS[i] = Wo[i];
    if (tid < 64) { boS[tid] = bo[tid]; seS[tid] = se ? se[b*64+tid] : 1.f; }
    __syncthreads();
    const int vl = tid>>2, p = tid&3;
    const int v = v0 + vl;
    const size_t row = ((size_t)t*NB + b)*512 + v;
    float acc[16];
    #pragma unroll
    for (int k=0;k<16;k++) acc[k] = 0.f;
    if (srcF16) {
        const f16* sp = (const f16*)src + row*Cin;
        for (int cc = 0; cc < Cin; cc++) {
            float xv = (float)sp[cc];
            #pragma unroll
            for (int k=0;k<16;k++) acc[k] += WoS[(p*16+k)*Cin + cc]*xv;
        }
    } else {
        const float* sp = (const float*)src + row*Cin;
        for (int cc = 0; cc < Cin; cc++) {
            float xv = sp[cc];
            #pragma unroll
            for (int k=0;k<16;k++) acc[k] += WoS[(p*16+k)*Cin + cc]*xv;
        }
    }
    alignas(16) f16 o16[16];
    #pragma unroll
    for (int k=0;k<16;k++) { int c = p*16+k; o16[k] = (f16)(seS[c]*(acc[k] + boS[c])); }
    f16* xp = X + row*64 + p*16;
    *(f32x4*)xp = *(f32x4*)o16;
    *(f32x4*)(xp+8) = *(f32x4*)(o16+8);
}

// ======================= layer 0 =======================
__global__ void k_xe(const float* __restrict__ x, const int* __restrict__ wt,
                     const float* __restrict__ Wemb, float* __restrict__ XE)
{
    int id = blockIdx.x*256 + threadIdx.x;
    if (id >= NT*NB*512) return;
    int v = id & 511; int r = id >> 9; int b = r & 31; int t = r >> 5;
    float vals[6] = {0.f,0.f,0.f,0.f,0.f,0.f};
    if (v < 500) {
        vals[0] = x[((size_t)(b*2+0)*500 + v)*24 + t];
        vals[1] = x[((size_t)(b*2+1)*500 + v)*24 + t];
        int wty = wt[((size_t)b*500 + v)*24 + t];
        vals[2] = Wemb[wty*4+0]; vals[3] = Wemb[wty*4+1];
        vals[4] = Wemb[wty*4+2]; vals[5] = Wemb[wty*4+3];
    }
    float* xe = XE + (size_t)id*6;
    #pragma unroll
    for (int c = 0; c < 6; c++) xe[c] = vals[c];
}

__global__ void k_seed0(const float* __restrict__ XE, f16* __restrict__ f0T,
                        f16* __restrict__ ccv0)
{
    int id = blockIdx.x*256 + threadIdx.x;
    if (id >= NB*512) return;
    int v = id & 511, b = id >> 9;
    const float* xe = XE + (size_t)id*6;
    #pragma unroll
    for (int c = 0; c < 6; c++) {
        f16 h = (v < 500) ? (f16)xe[c] : (f16)0.f;
        f0T[(size_t)id*42 + c] = h;
        ccv0[((size_t)b*6 + c)*512 + v] = h;
    }
}

__global__ __launch_bounds__(256)
void k_glstm0(f16* f0T, const float* __restrict__ Wg0,
              const float* __restrict__ bg0, float* __restrict__ cst0,
              float* __restrict__ hs0T, const float* __restrict__ XE,
              f16* __restrict__ ccv0, int t)
{
    __shared__ float WgS[24*42];
    __shared__ float bgS[24];
    int tid = threadIdx.x;
    for (int i = tid; i < 24*42; i += 256) WgS[i] = Wg0[i];
    if (tid < 24) bgS[tid] = bg0[tid];
    __syncthreads();
    int id = blockIdx.x*256 + tid;
    if (id >= NB*500) return;
    int b = id / 500, v = id - b*500;
    const f16* fp = f0T + ((size_t)b*512 + v)*42;
    float fv[42];
    #pragma unroll
    for (int g = 0; g < 42; g++) fv[g] = (float)fp[g];
    float gates[24];
    #pragma unroll
    for (int o = 0; o < 24; o++) {
        float a = bgS[o];
        #pragma unroll
        for (int g = 0; g < 42; g++) a += WgS[o*42+g]*fv[g];
        gates[o] = a;
    }
    size_t hrow = (((size_t)t*NB + b)*512 + v)*6;
    const float* xe = XE + (((size_t)(t+1)*NB + b)*512 + v)*6;   // only read if t<23
    #pragma unroll
    for (int c = 0; c < 6; c++) {
        size_t ci = ((size_t)b*500 + v)*6 + c;
        float cx = t ? cst0[ci] : 0.f;
        float cy = sigm(gates[6+c])*cx + sigm(gates[c])*gates[12+c];
        cst0[ci] = cy;
        float h = sigm(gates[18+c])*tanhf(cy);
        hs0T[hrow + c] = h;
        if (t < 23) {
            float cmb = xe[c] + h;
            f0T[((size_t)b*512 + v)*42 + c] = (f16)cmb;
            ccv0[((size_t)b*6 + c)*512 + v] = (f16)cmb;
        }
    }
}

// ======================= SE path =======================
__global__ void k_mean0(const float* __restrict__ hs0T, float* __restrict__ mean0)
{
    int b = blockIdx.x;
    float acc[6] = {0,0,0,0,0,0};
    for (int i = threadIdx.x; i < 24*500; i += 256) {
        int tt = i/500, v = i - tt*500;
        const float* p = hs0T + (((size_t)tt*NB + b)*512 + v)*6;
        #pragma unroll
        for (int c=0;c<6;c++) acc[c] += p[c];
    }
    __shared__ float red[256];
    for (int c=0;c<6;c++) {
        red[threadIdx.x] = acc[c]; __syncthreads();
        for (int s=128;s>0;s>>=1) { if (threadIdx.x<s) red[threadIdx.x]+=red[threadIdx.x+s]; __syncthreads(); }
        if (threadIdx.x==0) mean0[b*6+c] = red[0]/12000.f;
        __syncthreads();
    }
}

__global__ void k_mean1(const f16* __restrict__ hs1T, float* __restrict__ mean1)
{
    int cg = blockIdx.x, b = blockIdx.y;
    float acc[8] = {0,0,0,0,0,0,0,0};
    for (int i = threadIdx.x; i < 24*500; i += 256) {
        int tt = i/500, v = i - tt*500;
        const f16* p = hs1T + (((size_t)tt*NB + b)*512 + v)*64 + cg*8;
        #pragma unroll
        for (int c=0;c<8;c++) acc[c] += (float)p[c];
    }
    __shared__ float red[256];
    for (int c=0;c<8;c++) {
        red[threadIdx.x] = acc[c]; __syncthreads();
        for (int s=128;s>0;s>>=1) { if (threadIdx.x<s) red[threadIdx.x]+=red[threadIdx.x+s]; __syncthreads(); }
        if (threadIdx.x==0) mean1[b*64 + cg*8 + c] = red[0]/12000.f;
        __syncthreads();
    }
}

__global__ void k_se(const float* __restrict__ meanhs, const float* __restrict__ Wo,
                     const float* __restrict__ bo, int Cin,
                     const float* __restrict__ Wa, const float* __restrict__ Wb,
                     float* __restrict__ se)
{
    int b = blockIdx.x; int c = threadIdx.x;
    __shared__ float y[64]; __shared__ float a[4];
    float acc = bo[c];
    for (int j = 0; j < Cin; j++) acc += Wo[(size_t)c*Cin + j] * meanhs[b*Cin + j];
    y[c] = acc;
    __syncthreads();
    if (c < 4) {
        float s = 0.f;
        for (int j = 0; j < 64; j++) s += Wa[c*64 + j] * y[j];
        a[c] = fmaxf(s, 0.f);
    }
    __syncthreads();
    float s = 0.f;
    #pragma unroll
    for (int j = 0; j < 4; j++) s += Wb[c*4 + j] * a[j];
    se[b*64 + c] = 1.f/(1.f + expf(-s));
}

// ======================= host launch =======================
extern "C" void kernel_launch(void* const* d_in, const int* in_sizes, int n_in,
                              void* d_out, int out_size, void* d_ws, size_t ws_size,
                              hipStream_t stream)
{
    const float* x    = (const float*)d_in[0];
    const float* sup  = (const float*)d_in[1];
    const int*   wt   = (const int*)  d_in[2];
    const float* Wemb = (const float*)d_in[3];
    const float* Wg0  = (const float*)d_in[4];
    const float* bg0  = (const float*)d_in[5];
    const float* Wo0  = (const float*)d_in[6];
    const float* bo0  = (const float*)d_in[7];
    const float* Wa0  = (const float*)d_in[8];
    const float* Wb0  = (const float*)d_in[9];
    const float* Wg1  = (const float*)d_in[10];
    const float* bg1  = (const float*)d_in[11];
    const float* Wo1  = (const float*)d_in[12];
    const float* bo1  = (const float*)d_in[13];
    const float* Wa1  = (const float*)d_in[14];
    const float* Wb1  = (const float*)d_in[15];
    const float* Wg2  = (const float*)d_in[16];
    const float* bg2  = (const float*)d_in[17];
    const float* Wo2  = (const float*)d_in[18];
    const float* bo2  = (const float*)d_in[19];
    const float* Wg3  = (const float*)d_in[20];
    const float* bg3  = (const float*)d_in[21];
    const float* Wo3  = (const float*)d_in[22];
    const float* bo3  = (const float*)d_in[23];
    float* out = (float*)d_out;
    (void)in_sizes; (void)n_in; (void)out_size; (void)ws_size;

    char* ws = (char*)d_ws;
    size_t off = 0;
    f16*   AcatT  = (f16*)(ws + off);   off += (size_t)3072*512*2;
    float* A2     = (float*)(ws + off); off += (size_t)3*500*500*4;
    f16*   WgF1   = (f16*)(ws + off);   off += (size_t)256*448*2;
    f16*   WgF2   = (f16*)(ws + off);   off += (size_t)256*448*2;
    f16*   WgF3   = (f16*)(ws + off);   off += (size_t)256*448*2;
    f16*   comb_cv= (f16*)(ws + off);   off += (size_t)2048*512*2;
    f16*   ccv0   = (f16*)(ws + off);   off += (size_t)192*512*2;
    f16*   featsT = (f16*)(ws + off);   off += (size_t)NB*512*448*2;
    f16*   f0T    = (f16*)(ws + off);   off += (size_t)NB*512*42*2;
    float* XE     = (float*)(ws + off); off += (size_t)NT*NB*512*6*4;
    float* hs0T   = (float*)(ws + off); off += (size_t)NT*NB*512*6*4;
    f16*   hs1T   = (f16*)(ws + off);   off += (size_t)NT*NB*512*64*2;
    f16*   hT     = (f16*)(ws + off);   off += (size_t)NB*512*64*2;
    float* cstT   = (float*)(ws + off); off += (size_t)NB*512*64*4;
    float* cst0   = (float*)(ws + off); off += (size_t)NB*500*6*4;
    f16*   Xbuf   = (f16*)(ws + off);   off += (size_t)NT*NB*512*64*2;
    f16*   X3     = (f16*)(ws + off);   off += (size_t)NB*512*64*2;
    float* mean0  = (float*)(ws + off); off += 8192;
    float* se0    = (float*)(ws + off); off += 8192;
    float* mean1  = (float*)(ws + off); off += 8192;
    float* se1    = (float*)(ws + off); off += 8192;

    const size_t sliceH = (size_t)NB*512*64;   // f16 elements per timestep slice

    // ---- prep ----
    k_a2  <<<(3*500*500 + 255)/256, 256, 0, stream>>>(sup, A2);
    k_acat<<<(3072*512 + 255)/256, 256, 0, stream>>>(sup, A2, AcatT);
    k_f2h <<<(256*448 + 255)/256, 256, 0, stream>>>(Wg1, WgF1, 256*448);
    k_f2h <<<(256*448 + 255)/256, 256, 0, stream>>>(Wg2, WgF2, 256*448);
    k_f2h <<<(256*448 + 255)/256, 256, 0, stream>>>(Wg3, WgF3, 256*448);
    k_xe  <<<(NT*NB*512)/256, 256, 0, stream>>>(x, wt, Wemb, XE);

    // ---- layer 0 ----
    k_seed0<<<(NB*512)/256, 256, 0, stream>>>(XE, f0T, ccv0);
    for (int t = 0; t < NT; t++) {
        k_diff  <<<dim3(24, 2), 256, 0, stream>>>(ccv0, AcatT, f0T, 192, 6, 42);
        k_glstm0<<<(NB*500 + 255)/256, 256, 0, stream>>>(f0T, Wg0, bg0, cst0, hs0T, XE, ccv0, t);
    }
    k_mean0<<<NB, 256, 0, stream>>>(hs0T, mean0);
    k_se   <<<NB, 64, 0, stream>>>(mean0, Wo0, bo0, 6, Wa0, Wb0, se0);

    // ---- layer 1 ----
    k_xproj<<<dim3(8, NB, NT), 256, 0, stream>>>(hs0T, 0, 6, Wo0, bo0, se0, Xbuf);
    k_seed <<<dim3(8, NB), 256, 0, stream>>>(Xbuf, featsT, comb_cv);
    for (int t = 0; t < NT; t++) {
        k_diff <<<dim3(24, 16), 256, 0, stream>>>(comb_cv, AcatT, featsT, 2048, 64, 448);
        k_gateslstm<<<dim3(8, NB), 256, 0, stream>>>(featsT, WgF1, bg1, cstT,
                 (t < 23) ? Xbuf + (size_t)(t+1)*sliceH : (const f16*)nullptr,
                 hs1T + (size_t)t*sliceH, nullptr, nullptr, nullptr, t,
                 featsT, comb_cv, t == 0, t < 23);
    }
    k_mean1<<<dim3(8, NB), 256, 0, stream>>>(hs1T, mean1);
    k_se   <<<NB, 64, 0, stream>>>(mean1, Wo1, bo1, 64, Wa1, Wb1, se1);

    // ---- layer 2 ----
    k_xproj<<<dim3(8, NB, NT), 256, 0, stream>>>(hs1T, 1, 64, Wo1, bo1, se1, Xbuf);
    k_seed <<<dim3(8, NB), 256, 0, stream>>>(Xbuf, featsT, comb_cv);
    for (int t = 0; t < NT; t++) {
        k_diff <<<dim3(24, 16), 256, 0, stream>>>(comb_cv, AcatT, featsT, 2048, 64, 448);
        k_gateslstm<<<dim3(8, NB), 256, 0, stream>>>(featsT, WgF2, bg2, cstT,
                 (t < 23) ? Xbuf + (size_t)(t+1)*sliceH : (const f16*)nullptr,
                 (t == 23) ? hT : (f16*)nullptr, nullptr, nullptr, nullptr, t,
                 featsT, comb_cv, t == 0, t < 23);
    }

    // ---- layer 3 (final, fixed input x3 = Wo2.h2_last + bo2) ----
    k_xproj<<<dim3(8, NB, 1), 256, 0, stream>>>(hT, 1, 64, Wo2, bo2, nullptr, X3);
    k_seed <<<dim3(8, NB), 256, 0, stream>>>(X3, featsT, comb_cv);
    for (int t = 0; t < NT; t++) {
        k_diff <<<dim3(24, 16), 256, 0, stream>>>(comb_cv, AcatT, featsT, 2048, 64, 448);
        k_gateslstm<<<dim3(8, NB), 256, 0, stream>>>(featsT, WgF3, bg3, cstT,
                 X3, nullptr, Wo3, bo3, out, t,
                 featsT, comb_cv, t == 0, t < 23);
    }
}

// Round 3
// 4592.850 us; speedup vs baseline: 1.2566x; 1.0429x over previous
//
#include <hip/hip_runtime.h>
#include <math.h>

#define NV 500
#define NB 32
#define NT 24
#define NH 64

typedef _Float16 f16;
typedef _Float16 f16x8 __attribute__((ext_vector_type(8)));
typedef _Float16 f16x4 __attribute__((ext_vector_type(4)));
typedef float    f32x4 __attribute__((ext_vector_type(4)));

__device__ __forceinline__ float sigm(float x){ return 1.f/(1.f+expf(-x)); }

// ======================= prep kernels =======================
__global__ void k_a2(const float* __restrict__ A, float* __restrict__ A2)
{
    int idx = blockIdx.x*256 + threadIdx.x;
    if (idx >= 3*500*500) return;
    int wv = idx % 500; int rest = idx/500; int r = rest % 500; int s = rest/500;
    const float* Ar = A + ((size_t)s*500 + r)*500;
    const float* Ac = A + (size_t)s*500*500 + wv;
    float a = 0.f;
    for (int u = 0; u < 500; u++) a += Ar[u]*Ac[(size_t)u*500];
    A2[idx] = a;
}

__global__ void k_acat(const float* __restrict__ A, const float* __restrict__ A2,
                       f16* __restrict__ AcatT)
{
    int idx = blockIdx.x*256 + threadIdx.x;
    if (idx >= 3072*512) return;
    int k = idx & 511;     // v
    int n = idx >> 9;      // j*512 + w
    int j = n >> 9, wv = n & 511;
    float val = 0.f;
    if (k < 500 && wv < 500) {
        int s = j >> 1;
        const float* M = (j & 1) ? A2 : A;
        val = M[((size_t)s*500 + k)*500 + wv];
    }
    AcatT[idx] = (f16)val;
}

__global__ void k_f2h(const float* __restrict__ src, f16* __restrict__ dst, int n)
{
    int idx = blockIdx.x*256 + threadIdx.x;
    if (idx < n) dst[idx] = (f16)src[idx];
}

// ======================= MFMA diffusion GEMM (proven reg-staged structure) =======================
__global__ __launch_bounds__(256)
void k_diff(const f16* __restrict__ Acv, const f16* __restrict__ Bt,
            f16* __restrict__ fout, int Mtot, int C, int G)
{
    __shared__ f16 lA[128*32];
    __shared__ f16 lB[128*32];
    const int tid = threadIdx.x;
    const int n0 = blockIdx.x*128, m0 = blockIdx.y*128;
    const int r0 = tid>>2, c0 = tid&3;
    const int swz0 = r0*32 + ((c0 ^ ((r0>>1)&3))<<3);
    const int swz1 = swz0 + 64*32;
    int mA0 = m0 + r0;      if (mA0 > Mtot-1) mA0 = Mtot-1;
    int mA1 = m0 + r0 + 64; if (mA1 > Mtot-1) mA1 = Mtot-1;
    const f16* gA0 = Acv + (size_t)mA0*512 + c0*8;
    const f16* gA1 = Acv + (size_t)mA1*512 + c0*8;
    const f16* gB0 = Bt + (size_t)(n0+r0)*512 + c0*8;
    const f16* gB1 = Bt + (size_t)(n0+r0+64)*512 + c0*8;

    const int w = tid>>6, lane = tid&63;
    const int wr = (w>>1)<<6, wc = (w&1)<<6;
    const int fm = lane&15, fk = lane>>4;
    const int fch = (fk ^ ((fm>>1)&3))<<3;

    f32x4 acc[4][4];
    #pragma unroll
    for (int i=0;i<4;i++)
        #pragma unroll
        for (int j=0;j<4;j++) acc[i][j] = (f32x4){0.f,0.f,0.f,0.f};

    f32x4 ra0 = *(const f32x4*)gA0, ra1 = *(const f32x4*)gA1;
    f32x4 rb0 = *(const f32x4*)gB0, rb1 = *(const f32x4*)gB1;

    for (int ks = 0; ks < 16; ks++) {
        __syncthreads();
        *(f32x4*)(lA + swz0) = ra0;  *(f32x4*)(lA + swz1) = ra1;
        *(f32x4*)(lB + swz0) = rb0;  *(f32x4*)(lB + swz1) = rb1;
        if (ks < 15) {
            int o = (ks+1)*32;
            ra0 = *(const f32x4*)(gA0 + o); ra1 = *(const f32x4*)(gA1 + o);
            rb0 = *(const f32x4*)(gB0 + o); rb1 = *(const f32x4*)(gB1 + o);
        }
        __syncthreads();
        f16x8 af[4], bf[4];
        #pragma unroll
        for (int i=0;i<4;i++) af[i] = *(const f16x8*)(lA + (wr + i*16 + fm)*32 + fch);
        #pragma unroll
        for (int j=0;j<4;j++) bf[j] = *(const f16x8*)(lB + (wc + j*16 + fm)*32 + fch);
        #pragma unroll
        for (int i=0;i<4;i++)
            #pragma unroll
            for (int j=0;j<4;j++)
                acc[i][j] = __builtin_amdgcn_mfma_f32_16x16x32_f16(af[i], bf[j], acc[i][j], 0, 0, 0);
    }

    #pragma unroll
    for (int j=0;j<4;j++) {
        int col = n0 + wc + j*16 + fm;
        int jb = col >> 9, wv = col & 511;
        if (wv >= 500) continue;
        #pragma unroll
        for (int i=0;i<4;i++) {
            int mb = m0 + wr + i*16 + fk*4;
            if (C == 64) {
                if (mb >= Mtot) continue;
                int b = mb >> 6, c = mb & 63;
                f16x4 h4;
                h4[0]=(f16)acc[i][j][0]; h4[1]=(f16)acc[i][j][1];
                h4[2]=(f16)acc[i][j][2]; h4[3]=(f16)acc[i][j][3];
                *(f16x4*)(fout + ((size_t)b*512 + wv)*G + C + jb*C + c) = h4;
            } else {
                #pragma unroll
                for (int r=0;r<4;r++) {
                    int m = mb + r;
                    if (m < Mtot) {
                        int b = m / C, c = m - b*C;
                        fout[((size_t)b*512 + wv)*G + C + jb*C + c] = (f16)acc[i][j][r];
                    }
                }
            }
        }
    }
}

// ======================= fused gates GEMM + LSTM + next comb (layers 1-3) =======================
__global__ __launch_bounds__(256)
void k_gateslstm(const f16* __restrict__ fT, const f16* __restrict__ Wg,
                 const float* __restrict__ bg, float* __restrict__ cst,
                 const f16* __restrict__ Xn, f16* __restrict__ hsave,
                 const float* __restrict__ Wo3, const float* __restrict__ bo3,
                 float* __restrict__ out, int t,
                 f16* __restrict__ fTout, f16* __restrict__ ccv,
                 int first, int writecomb)
{
    __shared__ f16 lA[64*32];
    __shared__ f16 lB[256*32];
    __shared__ float ExF[4*64*65];   // [quad][vertex][chan] padded
    __shared__ float bgS[256];
    __shared__ f16 combS[64*68];
    const int tid = threadIdx.x;
    const int m0 = blockIdx.x*64, b = blockIdx.y;
    const f16* Ab = fT + (size_t)b*512*448;
    bgS[tid] = bg[tid];

    const int r0 = tid>>2, c0 = tid&3;
    const int swz = r0*32 + ((c0 ^ ((r0>>1)&3))<<3);
    const f16* gA = Ab + (size_t)(m0+r0)*448 + c0*8;
    const f16* gB = Wg + (size_t)r0*448 + c0*8;

    const int w = tid>>6, lane = tid&63;
    const int wc = w<<6;
    const int fm = lane&15, fk = lane>>4;
    const int fch = (fk ^ ((fm>>1)&3))<<3;

    f32x4 acc[4][4];
    #pragma unroll
    for (int i=0;i<4;i++)
        #pragma unroll
        for (int j=0;j<4;j++) acc[i][j] = (f32x4){0.f,0.f,0.f,0.f};

    f32x4 ra  = *(const f32x4*)gA;
    f32x4 rb0 = *(const f32x4*)gB;
    f32x4 rb1 = *(const f32x4*)(gB + (size_t)64*448);
    f32x4 rb2 = *(const f32x4*)(gB + (size_t)128*448);
    f32x4 rb3 = *(const f32x4*)(gB + (size_t)192*448);

    for (int ks = 0; ks < 14; ks++) {
        __syncthreads();
        *(f32x4*)(lA + swz) = ra;
        *(f32x4*)(lB + swz)          = rb0;
        *(f32x4*)(lB + 64*32 + swz)  = rb1;
        *(f32x4*)(lB + 128*32 + swz) = rb2;
        *(f32x4*)(lB + 192*32 + swz) = rb3;
        if (ks < 13) {
            int o = (ks+1)*32;
            ra  = *(const f32x4*)(gA + o);
            rb0 = *(const f32x4*)(gB + o);
            rb1 = *(const f32x4*)(gB + (size_t)64*448 + o);
            rb2 = *(const f32x4*)(gB + (size_t)128*448 + o);
            rb3 = *(const f32x4*)(gB + (size_t)192*448 + o);
        }
        __syncthreads();
        f16x8 af[4], bf[4];
        #pragma unroll
        for (int i=0;i<4;i++) af[i] = *(const f16x8*)(lA + (i*16 + fm)*32 + fch);
        #pragma unroll
        for (int j=0;j<4;j++) bf[j] = *(const f16x8*)(lB + (wc + j*16 + fm)*32 + fch);
        #pragma unroll
        for (int i=0;i<4;i++)
            #pragma unroll
            for (int j=0;j<4;j++)
                acc[i][j] = __builtin_amdgcn_mfma_f32_16x16x32_f16(af[i], bf[j], acc[i][j], 0, 0, 0);
    }

    // exchange accumulators: ExF[quad w][vertex][chan-within-quad]
    __syncthreads();
    #pragma unroll
    for (int i=0;i<4;i++)
        #pragma unroll
        for (int j=0;j<4;j++)
            #pragma unroll
            for (int r=0;r<4;r++)
                ExF[((w<<6) + i*16 + (fk<<2) + r)*65 + (j<<4) + fm] = acc[i][j][r];
    __syncthreads();

    // LSTM pointwise: thread owns 16 channels [p*16, p*16+16) of vertex vl
    const int vl = tid>>2, p = tid&3;
    const int v = m0 + vl;
    const size_t row = (size_t)b*512 + v;
    float hy[16];
    float* cp = cst + row*64 + (p<<4);
    #pragma unroll
    for (int k4=0;k4<4;k4++) {
        f32x4 cx4 = first ? (f32x4){0.f,0.f,0.f,0.f} : *(const f32x4*)(cp + k4*4);
        f32x4 cy4;
        #pragma unroll
        for (int e=0;e<4;e++) {
            int c = (p<<4) + k4*4 + e;
            float gi = ExF[(         vl)*65 + c] + bgS[c];
            float gf = ExF[( 64 +    vl)*65 + c] + bgS[64+c];
            float gc = ExF[(128 +    vl)*65 + c] + bgS[128+c];
            float go = ExF[(192 +    vl)*65 + c] + bgS[192+c];
            float cy = sigm(gf)*cx4[e] + sigm(gi)*gc;
            cy4[e] = cy;
            hy[k4*4+e] = sigm(go)*tanhf(cy);
        }
        *(f32x4*)(cp + k4*4) = cy4;
    }

    if (hsave) {
        alignas(16) f16 tmp[16];
        #pragma unroll
        for (int k=0;k<16;k++) tmp[k] = (f16)hy[k];
        f16* hp = hsave + row*64 + (p<<4);
        *(f32x4*)hp = *(f32x4*)tmp;
        *(f32x4*)(hp+8) = *(f32x4*)(tmp+8);
    }

    if (out) {
        float r0s = 0.f, r1s = 0.f;
        #pragma unroll
        for (int k=0;k<16;k++){ r0s += Wo3[(p<<4)+k]*hy[k]; r1s += Wo3[64+(p<<4)+k]*hy[k]; }
        r0s += __shfl_xor(r0s, 1, 64); r0s += __shfl_xor(r0s, 2, 64);
        r1s += __shfl_xor(r1s, 1, 64); r1s += __shfl_xor(r1s, 2, 64);
        if (p == 0 && v < 500) {
            out[((size_t)(b*2+0)*500 + v)*24 + t] = r0s + bo3[0];
            out[((size_t)(b*2+1)*500 + v)*24 + t] = r1s + bo3[1];
        }
    }

    if (writecomb) {
        alignas(16) f16 c16[16];
        if (v < 500) {
            const f16* xp = Xn + row*64 + (p<<4);
            alignas(16) f16 xv[16];
            *(f32x4*)xv = *(const f32x4*)xp;
            *(f32x4*)(xv+8) = *(const f32x4*)(xp+8);
            #pragma unroll
            for (int k=0;k<16;k++) c16[k] = (f16)((float)xv[k] + hy[k]);
        } else {
            #pragma unroll
            for (int k=0;k<16;k++) c16[k] = (f16)0.f;
        }
        f16* fp = fTout + row*448 + (p<<4);
        *(f32x4*)fp = *(f32x4*)c16;
        *(f32x4*)(fp+8) = *(f32x4*)(c16+8);
        #pragma unroll
        for (int k=0;k<16;k++) combS[vl*68 + (p<<4) + k] = c16[k];
        __syncthreads();
        const int c = tid>>2, jj = tid&3;
        alignas(16) f16 tmp[16];
        #pragma unroll
        for (int k=0;k<16;k++) tmp[k] = combS[(jj*16+k)*68 + c];
        f16* dst = ccv + ((size_t)b*64 + c)*512 + m0 + jj*16;
        *(f32x4*)dst = *(f32x4*)tmp;
        *(f32x4*)(dst+8) = *(f32x4*)(tmp+8);
    }
}

// ======================= seed comb for t=0 (big layers) =======================
__global__ __launch_bounds__(256)
void k_seed(const f16* __restrict__ X0, f16* __restrict__ fT, f16* __restrict__ ccv)
{
    __shared__ f16 combS[64*68];
    const int b = blockIdx.y, v0 = blockIdx.x*64;
    const int tid = threadIdx.x, vl = tid>>2, p = tid&3;
    const int v = v0 + vl;
    const size_t row = (size_t)b*512 + v;
    alignas(16) f16 c16[16];
    if (v < 500) {
        const f16* xp = X0 + row*64 + p*16;
        *(f32x4*)c16 = *(const f32x4*)xp;
        *(f32x4*)(c16+8) = *(const f32x4*)(xp+8);
    } else {
        #pragma unroll
        for (int k=0;k<16;k++) c16[k] = (f16)0.f;
    }
    f16* fp = fT + row*448 + p*16;
    *(f32x4*)fp = *(f32x4*)c16;
    *(f32x4*)(fp+8) = *(f32x4*)(c16+8);
    #pragma unroll
    for (int k=0;k<16;k++) combS[vl*68 + p*16 + k] = c16[k];
    __syncthreads();
    const int c = tid>>2, j = tid&3;
    alignas(16) f16 tmp[16];
    #pragma unroll
    for (int k=0;k<16;k++) tmp[k] = combS[(j*16+k)*68 + c];
    f16* dst = ccv + ((size_t)b*64 + c)*512 + v0 + j*16;
    *(f32x4*)dst = *(f32x4*)tmp;
    *(f32x4*)(dst+8) = *(f32x4*)(tmp+8);
}

// ======================= MFMA input projection (Cin=64, f16 src) =======================
// X[row][c] = se[b][c]*(sum_k src[row][k]*WoF[c][k] + bo[c]);  M rows = grid.x*128
__global__ __launch_bounds__(256)
void k_xprojm(const f16* __restrict__ src, const f16* __restrict__ WoF,
              const float* __restrict__ bo, const float* __restrict__ se,
              f16* __restrict__ X)
{
    __shared__ f16 lA[128*64];   // staging [ks][row][32]; reused as outS[row][64]
    __shared__ f16 lB[64*64];
    const int tid = threadIdx.x;
    const size_t m0 = (size_t)blockIdx.x*128;
    const int r0 = tid>>2, c0 = tid&3;
    const int swz = r0*32 + ((c0 ^ ((r0>>1)&3))<<3);
    const f16* gA0 = src + (m0 + r0)*64 + c0*8;
    const f16* gA1 = gA0 + 64*64;
    const f16* gB  = WoF + r0*64 + c0*8;

    *(f32x4*)(lA + swz)               = *(const f32x4*)gA0;          // ks0 rows 0-63
    *(f32x4*)(lA + 2048 + swz)        = *(const f32x4*)gA1;          // ks0 rows 64-127
    *(f32x4*)(lA + 4096 + swz)        = *(const f32x4*)(gA0 + 32);   // ks1 rows 0-63
    *(f32x4*)(lA + 6144 + swz)        = *(const f32x4*)(gA1 + 32);   // ks1 rows 64-127
    *(f32x4*)(lB + swz)               = *(const f32x4*)gB;           // ks0
    *(f32x4*)(lB + 2048 + swz)        = *(const f32x4*)(gB + 32);    // ks1
    __syncthreads();

    const int w = tid>>6, lane = tid&63;
    const int wr = w<<5;                 // 32 rows per wave
    const int fm = lane&15, fk = lane>>4;
    const int fch = (fk ^ ((fm>>1)&3))<<3;

    f32x4 acc[2][4];
    #pragma unroll
    for (int i=0;i<2;i++)
        #pragma unroll
        for (int j=0;j<4;j++) acc[i][j] = (f32x4){0.f,0.f,0.f,0.f};

    #pragma unroll
    for (int ks=0; ks<2; ks++) {
        f16x8 af[2], bf[4];
        #pragma unroll
        for (int i=0;i<2;i++) af[i] = *(const f16x8*)(lA + ks*4096 + (wr + i*16 + fm)*32 + fch);
        #pragma unroll
        for (int j=0;j<4;j++) bf[j] = *(const f16x8*)(lB + ks*2048 + (j*16 + fm)*32 + fch);
        #pragma unroll
        for (int i=0;i<2;i++)
            #pragma unroll
            for (int j=0;j<4;j++)
                acc[i][j] = __builtin_amdgcn_mfma_f32_16x16x32_f16(af[i], bf[j], acc[i][j], 0, 0, 0);
    }
    __syncthreads();   // lA reads done; reuse as output staging

    const int bb = (int)((m0 >> 9) & 31);   // 128-row tile lies in one (t,b) slice
    #pragma unroll
    for (int j=0;j<4;j++) {
        const int c = (j<<4) + fm;
        const float bias = bo[c];
        const float sf = se ? se[bb*64 + c] : 1.f;
        #pragma unroll
        for (int i=0;i<2;i++) {
            const int rbase = wr + i*16 + (fk<<2);
            #pragma unroll
            for (int r=0;r<4;r++)
                lA[(rbase + r)*64 + c] = (f16)(sf*(acc[i][j][r] + bias));
        }
    }
    __syncthreads();
    #pragma unroll
    for (int pass=0; pass<4; pass++) {
        int chunk = pass*256 + tid;
        int row = chunk>>3, off = (chunk&7)<<3;
        *(f32x4*)(X + (m0 + row)*64 + off) = *(const f32x4*)(lA + row*64 + off);
    }
}

// ======================= scalar input projection (Cin=6, f32 src, layer 1) =======================
__global__ void k_xproj1(const float* __restrict__ src, const float* __restrict__ Wo,
                         const float* __restrict__ bo, const float* __restrict__ se,
                         f16* __restrict__ X, int total)
{
    int id = blockIdx.x*256 + threadIdx.x;
    if (id >= total) return;
    int c = id & 63;
    size_t row = (size_t)(id >> 6);
    int b = (int)((row >> 9) & 31);
    const float* sp = src + row*6;
    float a = bo[c];
    #pragma unroll
    for (int j=0;j<6;j++) a += Wo[c*6+j]*sp[j];
    X[id] = (f16)(se[b*64+c]*a);
}

// ======================= layer 0 =======================
__global__ void k_xe(const float* __restrict__ x, const int* __restrict__ wt,
                     const float* __restrict__ Wemb, float* __restrict__ XE)
{
    int id = blockIdx.x*256 + threadIdx.x;
    if (id >= NT*NB*512) return;
    int v = id & 511; int r = id >> 9; int b = r & 31; int t = r >> 5;
    float vals[6] = {0.f,0.f,0.f,0.f,0.f,0.f};
    if (v < 500) {
        vals[0] = x[((size_t)(b*2+0)*500 + v)*24 + t];
        vals[1] = x[((size_t)(b*2+1)*500 + v)*24 + t];
        int wty = wt[((size_t)b*500 + v)*24 + t];
        vals[2] = Wemb[wty*4+0]; vals[3] = Wemb[wty*4+1];
        vals[4] = Wemb[wty*4+2]; vals[5] = Wemb[wty*4+3];
    }
    float* xe = XE + (size_t)id*6;
    #pragma unroll
    for (int c = 0; c < 6; c++) xe[c] = vals[c];
}

__global__ void k_seed0(const float* __restrict__ XE, f16* __restrict__ f0T,
                        f16* __restrict__ ccv0)
{
    int id = blockIdx.x*256 + threadIdx.x;
    if (id >= NB*512) return;
    int v = id & 511, b = id >> 9;
    const float* xe = XE + (size_t)id*6;
    #pragma unroll
    for (int c = 0; c < 6; c++) {
        f16 h = (v < 500) ? (f16)xe[c] : (f16)0.f;
        f0T[(size_t)id*42 + c] = h;
        ccv0[((size_t)b*6 + c)*512 + v] = h;
    }
}

__global__ __launch_bounds__(256)
void k_glstm0(f16* f0T, const float* __restrict__ Wg0,
              const float* __restrict__ bg0, float* __restrict__ cst0,
              float* __restrict__ hs0T, const float* __restrict__ XE,
              f16* __restrict__ ccv0, int t)
{
    __shared__ float WgS[24*42];
    __shared__ float bgS[24];
    int tid = threadIdx.x;
    for (int i = tid; i < 24*42; i += 256) WgS[i] = Wg0[i];
    if (tid < 24) bgS[tid] = bg0[tid];
    __syncthreads();
    int id = blockIdx.x*256 + tid;
    if (id >= NB*500) return;
    int b = id / 500, v = id - b*500;
    const f16* fp = f0T + ((size_t)b*512 + v)*42;
    float fv[42];
    #pragma unroll
    for (int g = 0; g < 42; g++) fv[g] = (float)fp[g];
    float gates[24];
    #pragma unroll
    for (int o = 0; o < 24; o++) {
        float a = bgS[o];
        #pragma unroll
        for (int g = 0; g < 42; g++) a += WgS[o*42+g]*fv[g];
        gates[o] = a;
    }
    size_t hrow = (((size_t)t*NB + b)*512 + v)*6;
    const float* xe = XE + (((size_t)(t+1)*NB + b)*512 + v)*6;   // only read if t<23
    #pragma unroll
    for (int c = 0; c < 6; c++) {
        size_t ci = ((size_t)b*500 + v)*6 + c;
        float cx = t ? cst0[ci] : 0.f;
        float cy = sigm(gates[6+c])*cx + sigm(gates[c])*gates[12+c];
        cst0[ci] = cy;
        float h = sigm(gates[18+c])*tanhf(cy);
        hs0T[hrow + c] = h;
        if (t < 23) {
            float cmb = xe[c] + h;
            f0T[((size_t)b*512 + v)*42 + c] = (f16)cmb;
            ccv0[((size_t)b*6 + c)*512 + v] = (f16)cmb;
        }
    }
}

// ======================= SE path =======================
__global__ void k_mean0(const float* __restrict__ hs0T, float* __restrict__ mean0)
{
    int b = blockIdx.x;
    float acc[6] = {0,0,0,0,0,0};
    for (int i = threadIdx.x; i < 24*500; i += 256) {
        int tt = i/500, v = i - tt*500;
        const float* p = hs0T + (((size_t)tt*NB + b)*512 + v)*6;
        #pragma unroll
        for (int c=0;c<6;c++) acc[c] += p[c];
    }
    __shared__ float red[256];
    for (int c=0;c<6;c++) {
        red[threadIdx.x] = acc[c]; __syncthreads();
        for (int s=128;s>0;s>>=1) { if (threadIdx.x<s) red[threadIdx.x]+=red[threadIdx.x+s]; __syncthreads(); }
        if (threadIdx.x==0) mean0[b*6+c] = red[0]/12000.f;
        __syncthreads();
    }
}

__global__ void k_mean1(const f16* __restrict__ hs1T, float* __restrict__ mean1)
{
    int cg = blockIdx.x, b = blockIdx.y;
    float acc[8] = {0,0,0,0,0,0,0,0};
    for (int i = threadIdx.x; i < 24*500; i += 256) {
        int tt = i/500, v = i - tt*500;
        const f16* p = hs1T + (((size_t)tt*NB + b)*512 + v)*64 + cg*8;
        #pragma unroll
        for (int c=0;c<8;c++) acc[c] += (float)p[c];
    }
    __shared__ float red[256];
    for (int c=0;c<8;c++) {
        red[threadIdx.x] = acc[c]; __syncthreads();
        for (int s=128;s>0;s>>=1) { if (threadIdx.x<s) red[threadIdx.x]+=red[threadIdx.x+s]; __syncthreads(); }
        if (threadIdx.x==0) mean1[b*64 + cg*8 + c] = red[0]/12000.f;
        __syncthreads();
    }
}

__global__ void k_se(const float* __restrict__ meanhs, const float* __restrict__ Wo,
                     const float* __restrict__ bo, int Cin,
                     const float* __restrict__ Wa, const float* __restrict__ Wb,
                     float* __restrict__ se)
{
    int b = blockIdx.x; int c = threadIdx.x;
    __shared__ float y[64]; __shared__ float a[4];
    float acc = bo[c];
    for (int j = 0; j < Cin; j++) acc += Wo[(size_t)c*Cin + j] * meanhs[b*Cin + j];
    y[c] = acc;
    __syncthreads();
    if (c < 4) {
        float s = 0.f;
        for (int j = 0; j < 64; j++) s += Wa[c*64 + j] * y[j];
        a[c] = fmaxf(s, 0.f);
    }
    __syncthreads();
    float s = 0.f;
    #pragma unroll
    for (int j = 0; j < 4; j++) s += Wb[c*4 + j] * a[j];
    se[b*64 + c] = 1.f/(1.f + expf(-s));
}

// ======================= host launch =======================
extern "C" void kernel_launch(void* const* d_in, const int* in_sizes, int n_in,
                              void* d_out, int out_size, void* d_ws, size_t ws_size,
                              hipStream_t stream)
{
    const float* x    = (const float*)d_in[0];
    const float* sup  = (const float*)d_in[1];
    const int*   wt   = (const int*)  d_in[2];
    const float* Wemb = (const float*)d_in[3];
    const float* Wg0  = (const float*)d_in[4];
    const float* bg0  = (const float*)d_in[5];
    const float* Wo0  = (const float*)d_in[6];
    const float* bo0  = (const float*)d_in[7];
    const float* Wa0  = (const float*)d_in[8];
    const float* Wb0  = (const float*)d_in[9];
    const float* Wg1  = (const float*)d_in[10];
    const float* bg1  = (const float*)d_in[11];
    const float* Wo1  = (const float*)d_in[12];
    const float* bo1  = (const float*)d_in[13];
    const float* Wa1  = (const float*)d_in[14];
    const float* Wb1  = (const float*)d_in[15];
    const float* Wg2  = (const float*)d_in[16];
    const float* bg2  = (const float*)d_in[17];
    const float* Wo2  = (const float*)d_in[18];
    const float* bo2  = (const float*)d_in[19];
    const float* Wg3  = (const float*)d_in[20];
    const float* bg3  = (const float*)d_in[21];
    const float* Wo3  = (const float*)d_in[22];
    const float* bo3  = (const float*)d_in[23];
    float* out = (float*)d_out;
    (void)in_sizes; (void)n_in; (void)out_size; (void)ws_size;

    char* ws = (char*)d_ws;
    size_t off = 0;
    f16*   AcatT  = (f16*)(ws + off);   off += (size_t)3072*512*2;
    float* A2     = (float*)(ws + off); off += (size_t)3*500*500*4;
    f16*   WgF1   = (f16*)(ws + off);   off += (size_t)256*448*2;
    f16*   WgF2   = (f16*)(ws + off);   off += (size_t)256*448*2;
    f16*   WgF3   = (f16*)(ws + off);   off += (size_t)256*448*2;
    f16*   WoF1   = (f16*)(ws + off);   off += (size_t)64*64*2;
    f16*   WoF2   = (f16*)(ws + off);   off += (size_t)64*64*2;
    f16*   comb_cv= (f16*)(ws + off);   off += (size_t)2048*512*2;
    f16*   ccv0   = (f16*)(ws + off);   off += (size_t)192*512*2;
    f16*   featsT = (f16*)(ws + off);   off += (size_t)NB*512*448*2;
    f16*   f0T    = (f16*)(ws + off);   off += (size_t)NB*512*42*2;
    float* XE     = (float*)(ws + off); off += (size_t)NT*NB*512*6*4;
    float* hs0T   = (float*)(ws + off); off += (size_t)NT*NB*512*6*4;
    f16*   hs1T   = (f16*)(ws + off);   off += (size_t)NT*NB*512*64*2;
    f16*   hT     = (f16*)(ws + off);   off += (size_t)NB*512*64*2;
    float* cstT   = (float*)(ws + off); off += (size_t)NB*512*64*4;
    float* cst0   = (float*)(ws + off); off += (size_t)NB*500*6*4;
    f16*   Xbuf   = (f16*)(ws + off);   off += (size_t)NT*NB*512*64*2;
    f16*   X3     = (f16*)(ws + off);   off += (size_t)NB*512*64*2;
    float* mean0  = (float*)(ws + off); off += 8192;
    float* se0    = (float*)(ws + off); off += 8192;
    float* mean1  = (float*)(ws + off); off += 8192;
    float* se1    = (float*)(ws + off); off += 8192;

    const size_t sliceH = (size_t)NB*512*64;   // f16 elements per timestep slice

    // ---- prep ----
    k_a2  <<<(3*500*500 + 255)/256, 256, 0, stream>>>(sup, A2);
    k_acat<<<(3072*512 + 255)/256, 256, 0, stream>>>(sup, A2, AcatT);
    k_f2h <<<(256*448 + 255)/256, 256, 0, stream>>>(Wg1, WgF1, 256*448);
    k_f2h <<<(256*448 + 255)/256, 256, 0, stream>>>(Wg2, WgF2, 256*448);
    k_f2h <<<(256*448 + 255)/256, 256, 0, stream>>>(Wg3, WgF3, 256*448);
    k_f2h <<<16, 256, 0, stream>>>(Wo1, WoF1, 64*64);
    k_f2h <<<16, 256, 0, stream>>>(Wo2, WoF2, 64*64);
    k_xe  <<<(NT*NB*512)/256, 256, 0, stream>>>(x, wt, Wemb, XE);

    // ---- layer 0 ----
    k_seed0<<<(NB*512)/256, 256, 0, stream>>>(XE, f0T, ccv0);
    for (int t = 0; t < NT; t++) {
        k_diff  <<<dim3(24, 2), 256, 0, stream>>>(ccv0, AcatT, f0T, 192, 6, 42);
        k_glstm0<<<(NB*500 + 255)/256, 256, 0, stream>>>(f0T, Wg0, bg0, cst0, hs0T, XE, ccv0, t);
    }
    k_mean0<<<NB, 256, 0, stream>>>(hs0T, mean0);
    k_se   <<<NB, 64, 0, stream>>>(mean0, Wo0, bo0, 6, Wa0, Wb0, se0);

    // ---- layer 1 ----
    k_xproj1<<<(NT*NB*512*64)/256, 256, 0, stream>>>(hs0T, Wo0, bo0, se0, Xbuf, NT*NB*512*64);
    k_seed <<<dim3(8, NB), 256, 0, stream>>>(Xbuf, featsT, comb_cv);
    for (int t = 0; t < NT; t++) {
        k_diff <<<dim3(24, 16), 256, 0, stream>>>(comb_cv, AcatT, featsT, 2048, 64, 448);
        k_gateslstm<<<dim3(8, NB), 256, 0, stream>>>(featsT, WgF1, bg1, cstT,
                 (t < 23) ? Xbuf + (size_t)(t+1)*sliceH : (const f16*)nullptr,
                 hs1T + (size_t)t*sliceH, nullptr, nullptr, nullptr, t,
                 featsT, comb_cv, t == 0, t < 23);
    }
    k_mean1<<<dim3(8, NB), 256, 0, stream>>>(hs1T, mean1);
    k_se   <<<NB, 64, 0, stream>>>(mean1, Wo1, bo1, 64, Wa1, Wb1, se1);

    // ---- layer 2 ----
    k_xprojm<<<(NT*NB*512)/128, 256, 0, stream>>>(hs1T, WoF1, bo1, se1, Xbuf);
    k_seed <<<dim3(8, NB), 256, 0, stream>>>(Xbuf, featsT, comb_cv);
    for (int t = 0; t < NT; t++) {
        k_diff <<<dim3(24, 16), 256, 0, stream>>>(comb_cv, AcatT, featsT, 2048, 64, 448);
        k_gateslstm<<<dim3(8, NB), 256, 0, stream>>>(featsT, WgF2, bg2, cstT,
                 (t < 23) ? Xbuf + (size_t)(t+1)*sliceH : (const f16*)nullptr,
                 (t == 23) ? hT : (f16*)nullptr, nullptr, nullptr, nullptr, t,
                 featsT, comb_cv, t == 0, t < 23);
    }

    // ---- layer 3 (final, fixed input x3 = Wo2.h2_last + bo2) ----
    k_xprojm<<<(NB*512)/128, 256, 0, stream>>>(hT, WoF2, bo2, nullptr, X3);
    k_seed <<<dim3(8, NB), 256, 0, stream>>>(X3, featsT, comb_cv);
    for (int t = 0; t < NT; t++) {
        k_diff <<<dim3(24, 16), 256, 0, stream>>>(comb_cv, AcatT, featsT, 2048, 64, 448);
        k_gateslstm<<<dim3(8, NB), 256, 0, stream>>>(featsT, WgF3, bg3, cstT,
                 X3, nullptr, Wo3, bo3, out, t,
                 featsT, comb_cv, t == 0, t < 23);
    }
}